// Round 13
// baseline (163.866 us; speedup 1.0000x reference)
//
#include <hip/hip_runtime.h>
#include <math.h>
#include <stdint.h>

#define S_    128
#define B_    128
#define E_    64
#define H_    8
#define T_    12
#define FAN_  72
#define NOPS_ 30
#define MAXG_ 30
#define NROWS_ (S_ * B_)

// ===========================================================================
// COMPILE-TIME circuit (validated r8-r12): MT19937(1234) + optimizer.
// ===========================================================================
constexpr double CT_PI = 3.14159265358979323846;

constexpr double ct_cos(double x) {
    double t = 1.0, s = 1.0, x2 = x * x;
    for (int k = 1; k <= 20; k++) { t *= -x2 / ((2.0*k - 1.0) * (2.0*k)); s += t; }
    return s;
}
constexpr double ct_sin(double x) {
    double t = x, s = x, x2 = x * x;
    for (int k = 1; k <= 20; k++) { t *= -x2 / ((2.0*k) * (2.0*k + 1.0)); s += t; }
    return s;
}

constexpr void ct_mmul(const double* A, const double* B, double* C) {
    for (int i = 0; i < 2; i++)
        for (int j = 0; j < 2; j++) {
            double rr = 0.0, ii = 0.0;
            for (int k = 0; k < 2; k++) {
                double ar = A[(i*2+k)*2], ai = A[(i*2+k)*2+1];
                double br = B[(k*2+j)*2], bi = B[(k*2+j)*2+1];
                rr += ar*br - ai*bi;
                ii += ar*bi + ai*br;
            }
            C[(i*2+j)*2] = rr; C[(i*2+j)*2+1] = ii;
        }
}

struct CTC {
    int n;
    int type[MAXG_];
    int w1[MAXG_];
    int w2[MAXG_];
    double U[MAXG_][8];
    double initM[8][8];
    double endM[8][8];
};

constexpr CTC build_ct() {
    uint32_t mt[624] = {};
    int idx = 624;
    {
        uint32_t s = 1234u;
        for (int i = 0; i < 624; i++) {
            mt[i] = s;
            s = 1812433253u * (s ^ (s >> 30)) + (uint32_t)i + 1u;
        }
    }
    auto nextf = [&]() -> uint32_t {
        if (idx >= 624) {
            for (int i = 0; i < 624; i++) {
                uint32_t y = (mt[i] & 0x80000000u) | (mt[(i+1)%624] & 0x7fffffffu);
                uint32_t v = mt[(i+397)%624] ^ (y >> 1);
                mt[i] = (y & 1u) ? (v ^ 0x9908b0dfu) : v;
            }
            idx = 0;
        }
        uint32_t y = mt[idx++];
        y ^= y >> 11;
        y ^= (y << 7)  & 0x9d2c5680u;
        y ^= (y << 15) & 0xefc60000u;
        y ^= y >> 18;
        return y;
    };
    auto randint = [&](uint32_t n) -> uint32_t {
        uint32_t rng = n - 1u, mask = rng;
        mask |= mask >> 1; mask |= mask >> 2; mask |= mask >> 4;
        mask |= mask >> 8; mask |= mask >> 16;
        uint32_t v = 0;
        do { v = nextf() & mask; } while (v > rng);
        return v;
    };
    auto uniform2pi = [&]() -> double {
        uint32_t a = nextf() >> 5;
        uint32_t b = nextf() >> 6;
        double d = ((double)a * 67108864.0 + (double)b) / 9007199254740992.0;
        return 2.0 * CT_PI * d;
    };

    int kindA[NOPS_] = {}, aA[NOPS_] = {}, bA[NOPS_] = {};
    double UA[NOPS_][8] = {};
    for (int i = 0; i < NOPS_; i++) {
        uint32_t kind = randint(4);
        if (kind == 3u) {
            int c = (int)randint(8);
            int t = (int)randint(7);
            if (t >= c) t += 1;
            kindA[i] = 1; aA[i] = c; bA[i] = t;
            UA[i][0] = 1.0; UA[i][6] = 1.0;
        } else {
            int g = (int)(kind % 3u);
            int w = (int)randint(8);
            double th = uniform2pi();
            double c = ct_cos(0.5 * th), s = ct_sin(0.5 * th);
            kindA[i] = 0; aA[i] = w; bA[i] = -1;
            if (g == 0)      { UA[i][0]=c;  UA[i][3]=-s; UA[i][5]=-s; UA[i][6]=c; }
            else if (g == 1) { UA[i][0]=c;  UA[i][2]=-s; UA[i][4]= s; UA[i][6]=c; }
            else             { UA[i][0]=c;  UA[i][1]=-s; UA[i][6]= c; UA[i][7]=s; }
        }
    }

    int ikind[MAXG_] = {}, ia[MAXG_] = {}, ib[MAXG_] = {};
    double iU[MAXG_][8] = {};
    int cnt = 0;
    double initM[8][8] = {}, endM[8][8] = {};
    for (int w = 0; w < 8; w++) { initM[w][0] = 1.0; initM[w][6] = 1.0;
                                  endM[w][0]  = 1.0; endM[w][6]  = 1.0; }

    for (int oi = 0; oi < NOPS_; oi++) {
        if (kindA[oi] == 0) {
            int w = aA[oi], k = cnt - 1;
            bool merged = false;
            while (k >= 0) {
                if (ikind[k] == 0) {
                    if (ia[k] == w) {
                        double tmp[8] = {};
                        ct_mmul(UA[oi], iU[k], tmp);
                        for (int j = 0; j < 8; j++) iU[k][j] = tmp[j];
                        merged = true; break;
                    }
                    k--;
                } else {
                    if (w == ia[k] || w == ib[k]) break;
                    k--;
                }
            }
            if (merged) continue;
            if (k < 0) {
                double tmp[8] = {};
                ct_mmul(UA[oi], initM[w], tmp);
                for (int j = 0; j < 8; j++) initM[w][j] = tmp[j];
                continue;
            }
            ikind[cnt] = 0; ia[cnt] = w; ib[cnt] = -1;
            for (int j = 0; j < 8; j++) iU[cnt][j] = UA[oi][j];
            cnt++;
        } else {
            int c = aA[oi], t2 = bA[oi], k = cnt - 1;
            bool cancelled = false;
            while (k >= 0) {
                if (ikind[k] == 0) {
                    int w = ia[k];
                    if (w == c || w == t2) break;
                    k--;
                } else {
                    int c2 = ia[k], tt = ib[k];
                    if (c2 == c && tt == t2) {
                        for (int m = k; m < cnt - 1; m++) {
                            ikind[m] = ikind[m+1]; ia[m] = ia[m+1]; ib[m] = ib[m+1];
                            for (int j = 0; j < 8; j++) iU[m][j] = iU[m+1][j];
                        }
                        cnt--; cancelled = true; break;
                    }
                    if (c2 != t2 && tt != c) k--;
                    else break;
                }
            }
            if (!cancelled) {
                ikind[cnt] = 1; ia[cnt] = c; ib[cnt] = t2;
                for (int j = 0; j < 8; j++) iU[cnt][j] = 0.0;
                iU[cnt][0] = 1.0; iU[cnt][6] = 1.0;
                cnt++;
            }
        }
    }
    bool blocked[8] = {};
    for (int k = cnt - 1; k >= 0; k--) {
        if (ikind[k] == 0) {
            int w = ia[k];
            if (!blocked[w]) {
                double tmp[8] = {};
                ct_mmul(endM[w], iU[k], tmp);
                for (int j = 0; j < 8; j++) endM[w][j] = tmp[j];
                for (int m = k; m < cnt - 1; m++) {
                    ikind[m] = ikind[m+1]; ia[m] = ia[m+1]; ib[m] = ib[m+1];
                    for (int j = 0; j < 8; j++) iU[m][j] = iU[m+1][j];
                }
                cnt--;
            }
        } else {
            blocked[ia[k]] = true; blocked[ib[k]] = true;
        }
    }

    CTC q = {};
    q.n = cnt;
    for (int i = 0; i < cnt; i++) {
        q.type[i] = ikind[i]; q.w1[i] = ia[i]; q.w2[i] = ib[i];
        for (int j = 0; j < 8; j++) q.U[i][j] = iU[i][j];
    }
    for (int w = 0; w < 8; w++)
        for (int j = 0; j < 8; j++) { q.initM[w][j] = initM[w][j]; q.endM[w][j] = endM[w][j]; }
    return q;
}

constexpr CTC CIRC = build_ct();

// ===========================================================================
// Device helpers (validated r5-r12)
// ===========================================================================
// Rational gates for the serial scan: Pade(7,6) tanh, 1 transcendental (rcp)
// per gate instead of 2 serial (exp2 then rcp). |err| <= 2e-4 with clamp.
__device__ __forceinline__ float rat_tanh(float x) {
    x = fminf(4.6f, fmaxf(-4.6f, x));
    float x2 = x * x;
    float n = fmaf(fmaf(x2 + 378.f, x2, 17325.f), x2, 135135.f);
    float d = fmaf(fmaf(fmaf(x2, 28.f, 3150.f), x2, 62370.f), x2, 135135.f);
    return x * n * __builtin_amdgcn_rcpf(d);
}
__device__ __forceinline__ float rat_sigmoid(float x) {
    return fmaf(rat_tanh(0.5f * x), 0.5f, 0.5f);
}

template<int CTRL>
__device__ __forceinline__ float dppf(float x) {
    union { float f; int i; } u, r;
    u.f = x;
    r.i = __builtin_amdgcn_update_dpp(u.i, u.i, CTRL, 0xF, 0xF, true);
    return r.f;
}

template<int M>
__device__ __forceinline__ float lane_xor(float x, int lane) {
    if constexpr (M == 1)  return dppf<0xB1>(x);
    else if constexpr (M == 2) return dppf<0x4E>(x);
    else if constexpr (M == 4) {
        float a = dppf<0x104>(x);
        float b = dppf<0x114>(x);
        return (lane & 4) ? b : a;
    }
    else if constexpr (M == 8) return dppf<0x128>(x);
    else return __shfl_xor(x, M, 64);
}

template<int W>
__device__ __forceinline__ float exch(float x, int lane) {
    if constexpr (W == 0) return __shfl_xor(x, 32, 64);
    else if constexpr (W == 1) return __shfl_xor(x, 16, 64);
    else if constexpr (W == 2) return lane_xor<8>(x, lane);
    else if constexpr (W == 3) return lane_xor<4>(x, lane);
    else if constexpr (W == 4) return lane_xor<2>(x, lane);
    else return lane_xor<1>(x, lane);
}

template<int W>
__device__ __forceinline__ int qbit_ct(int lane, int j) {
    if constexpr (W < 6) return (lane >> (5 - W)) & 1;
    else if constexpr (W == 6) return (j >> 1) & 1;
    else return j & 1;
}

__device__ __forceinline__ void pair_rt(float u0, float u1, float u2, float u3,
                                        float u4, float u5, float u6, float u7,
                                        float& a0r, float& a0i, float& a1r, float& a1i) {
    float n0r = u0*a0r - u1*a0i + u2*a1r - u3*a1i;
    float n0i = u0*a0i + u1*a0r + u2*a1i + u3*a1r;
    float n1r = u4*a0r - u5*a0i + u6*a1r - u7*a1i;
    float n1i = u4*a0i + u5*a0r + u6*a1i + u7*a1r;
    a0r = n0r; a0i = n0i; a1r = n1r; a1i = n1i;
}

template<int W>
__device__ __forceinline__ void gate_rt(float u0, float u1, float u2, float u3,
                                        float u4, float u5, float u6, float u7,
                                        int lane, float ar[4], float ai[4]) {
    if constexpr (W < 6) {
        const int b = (lane >> (5 - W)) & 1;
        const float dr  = b ? u6 : u0;
        const float di  = b ? u7 : u1;
        const float onr = b ? u4 : u2;
        const float oni = b ? u5 : u3;
        #pragma unroll
        for (int j = 0; j < 4; j++) {
            float br = exch<W>(ar[j], lane);
            float bi = exch<W>(ai[j], lane);
            float nr = dr * ar[j] - di * ai[j] + onr * br - oni * bi;
            float ni = dr * ai[j] + di * ar[j] + onr * bi + oni * br;
            ar[j] = nr; ai[j] = ni;
        }
    } else if constexpr (W == 6) {
        pair_rt(u0,u1,u2,u3,u4,u5,u6,u7, ar[0], ai[0], ar[2], ai[2]);
        pair_rt(u0,u1,u2,u3,u4,u5,u6,u7, ar[1], ai[1], ar[3], ai[3]);
    } else {
        pair_rt(u0,u1,u2,u3,u4,u5,u6,u7, ar[0], ai[0], ar[1], ai[1]);
        pair_rt(u0,u1,u2,u3,u4,u5,u6,u7, ar[2], ai[2], ar[3], ai[3]);
    }
}

template<int CW, int TW>
__device__ __forceinline__ void cnot_ct(int lane, float ar[4], float ai[4]) {
    if constexpr (TW < 6) {
        #pragma unroll
        for (int j = 0; j < 4; j++) {
            float br = exch<TW>(ar[j], lane);
            float bi = exch<TW>(ai[j], lane);
            int ctrl = qbit_ct<CW>(lane, j);
            ar[j] = ctrl ? br : ar[j];
            ai[j] = ctrl ? bi : ai[j];
        }
    } else if constexpr (TW == 6) {
        int cA = qbit_ct<CW>(lane, 0), cB = qbit_ct<CW>(lane, 1);
        float n0r = cA ? ar[2] : ar[0], n0i = cA ? ai[2] : ai[0];
        float n2r = cA ? ar[0] : ar[2], n2i = cA ? ai[0] : ai[2];
        float n1r = cB ? ar[3] : ar[1], n1i = cB ? ai[3] : ai[1];
        float n3r = cB ? ar[1] : ar[3], n3i = cB ? ai[1] : ai[3];
        ar[0]=n0r; ai[0]=n0i; ar[1]=n1r; ai[1]=n1i;
        ar[2]=n2r; ai[2]=n2i; ar[3]=n3r; ai[3]=n3i;
    } else {
        int cA = qbit_ct<CW>(lane, 0), cB = qbit_ct<CW>(lane, 2);
        float n0r = cA ? ar[1] : ar[0], n0i = cA ? ai[1] : ai[0];
        float n1r = cA ? ar[0] : ar[1], n1i = cA ? ai[0] : ai[1];
        float n2r = cB ? ar[3] : ar[2], n2i = cB ? ai[3] : ai[2];
        float n3r = cB ? ar[2] : ar[3], n3i = cB ? ai[2] : ai[3];
        ar[0]=n0r; ai[0]=n0i; ar[1]=n1r; ai[1]=n1i;
        ar[2]=n2r; ai[2]=n2i; ar[3]=n3r; ai[3]=n3i;
    }
}

template<int I>
__device__ __forceinline__ void gate_op(int lane, float ar[4], float ai[4]) {
    constexpr int w = CIRC.w1[I];
    constexpr float u0 = (float)CIRC.U[I][0], u1 = (float)CIRC.U[I][1];
    constexpr float u2 = (float)CIRC.U[I][2], u3 = (float)CIRC.U[I][3];
    constexpr float u4 = (float)CIRC.U[I][4], u5 = (float)CIRC.U[I][5];
    constexpr float u6 = (float)CIRC.U[I][6], u7 = (float)CIRC.U[I][7];
    gate_rt<w>(u0,u1,u2,u3,u4,u5,u6,u7, lane, ar, ai);
}

template<int I>
__device__ __forceinline__ void run_ops(int lane, float ar[4], float ai[4]) {
    if constexpr (I < CIRC.n) {
        if constexpr (CIRC.type[I] == 0) gate_op<I>(lane, ar, ai);
        else cnot_ct<CIRC.w1[I], CIRC.w2[I]>(lane, ar, ai);
        run_ops<I + 1>(lane, ar, ai);
    }
}

struct V2 { float r0, i0, r1, i1; };
template<int W>
__device__ __forceinline__ V2 init_wire(float th) {
    constexpr float m0 = (float)CIRC.initM[W][0], m1 = (float)CIRC.initM[W][1];
    constexpr float m2 = (float)CIRC.initM[W][2], m3 = (float)CIRC.initM[W][3];
    constexpr float m4 = (float)CIRC.initM[W][4], m5 = (float)CIRC.initM[W][5];
    constexpr float m6 = (float)CIRC.initM[W][6], m7 = (float)CIRC.initM[W][7];
    float c = __cosf(th), s = __sinf(th);
    V2 v;
    v.r0 = m0*c + m2*s; v.i0 = m1*c + m3*s;
    v.r1 = m4*c + m6*s; v.i1 = m5*c + m7*s;
    return v;
}

template<int W>
__device__ __forceinline__ void final_wire(float c, float s, int lane,
                                           float ar[4], float ai[4]) {
    constexpr float E0 = (float)CIRC.endM[W][0], E1 = (float)CIRC.endM[W][1];
    constexpr float E2 = (float)CIRC.endM[W][2], E3 = (float)CIRC.endM[W][3];
    constexpr float E4 = (float)CIRC.endM[W][4], E5 = (float)CIRC.endM[W][5];
    constexpr float E6 = (float)CIRC.endM[W][6], E7 = (float)CIRC.endM[W][7];
    float F0 =  c*E0 + s*E5;
    float F1 =  c*E1 - s*E4;
    float F2 =  c*E2 + s*E7;
    float F3 =  c*E3 - s*E6;
    float F4 =  s*E1 + c*E4;
    float F5 = -s*E0 + c*E5;
    float F6 =  s*E3 + c*E6;
    float F7 = -s*E2 + c*E7;
    gate_rt<W>(F0,F1,F2,F3,F4,F5,F6,F7, lane, ar, ai);
}

// stride-2 all-gather of 8 values (validated r10-r12)
__device__ __forceinline__ void bcast8_s2(float v, int lane, float h[8]) {
    float p  = lane_xor<2>(v, lane);
    float a0 = (lane & 2) ? p : v;
    float a1 = (lane & 2) ? v : p;
    float q0 = lane_xor<4>(a0, lane);
    float q1 = lane_xor<4>(a1, lane);
    float b0 = (lane & 4) ? q0 : a0;
    float b1 = (lane & 4) ? q1 : a1;
    float b2 = (lane & 4) ? a0 : q0;
    float b3 = (lane & 4) ? a1 : q1;
    float r0 = lane_xor<8>(b0, lane);
    float r1 = lane_xor<8>(b1, lane);
    float r2 = lane_xor<8>(b2, lane);
    float r3 = lane_xor<8>(b3, lane);
    h[0] = (lane & 8) ? r0 : b0;  h[1] = (lane & 8) ? r1 : b1;
    h[2] = (lane & 8) ? r2 : b2;  h[3] = (lane & 8) ? r3 : b3;
    h[4] = (lane & 8) ? b0 : r0;  h[5] = (lane & 8) ? b1 : r1;
    h[6] = (lane & 8) ? b2 : r2;  h[7] = (lane & 8) ? b3 : r3;
}

// QFC body for one row (validated r8-r12)
__device__ __forceinline__ void qfc_row(const float th[8],
    float cq[8], float sq[8], int lane,
    const float* __restrict__ Whead, const float* __restrict__ b_head,
    float* __restrict__ outrow)
{
    float ar[4], ai[4];
    {
        V2 v0 = init_wire<0>(th[0]);
        V2 v1 = init_wire<1>(th[1]);
        V2 v2 = init_wire<2>(th[2]);
        V2 v3 = init_wire<3>(th[3]);
        V2 v4 = init_wire<4>(th[4]);
        V2 v5 = init_wire<5>(th[5]);
        V2 v6 = init_wire<6>(th[6]);
        V2 v7 = init_wire<7>(th[7]);
        float Pr = 1.f, Pi = 0.f;
        {
            int bit = (lane >> 5) & 1;
            float er = bit ? v0.r1 : v0.r0, ei = bit ? v0.i1 : v0.i0;
            float nr = Pr*er - Pi*ei, ni = Pr*ei + Pi*er; Pr = nr; Pi = ni;
        }
        {
            int bit = (lane >> 4) & 1;
            float er = bit ? v1.r1 : v1.r0, ei = bit ? v1.i1 : v1.i0;
            float nr = Pr*er - Pi*ei, ni = Pr*ei + Pi*er; Pr = nr; Pi = ni;
        }
        {
            int bit = (lane >> 3) & 1;
            float er = bit ? v2.r1 : v2.r0, ei = bit ? v2.i1 : v2.i0;
            float nr = Pr*er - Pi*ei, ni = Pr*ei + Pi*er; Pr = nr; Pi = ni;
        }
        {
            int bit = (lane >> 2) & 1;
            float er = bit ? v3.r1 : v3.r0, ei = bit ? v3.i1 : v3.i0;
            float nr = Pr*er - Pi*ei, ni = Pr*ei + Pi*er; Pr = nr; Pi = ni;
        }
        {
            int bit = (lane >> 1) & 1;
            float er = bit ? v4.r1 : v4.r0, ei = bit ? v4.i1 : v4.i0;
            float nr = Pr*er - Pi*ei, ni = Pr*ei + Pi*er; Pr = nr; Pi = ni;
        }
        {
            int bit = lane & 1;
            float er = bit ? v5.r1 : v5.r0, ei = bit ? v5.i1 : v5.i0;
            float nr = Pr*er - Pi*ei, ni = Pr*ei + Pi*er; Pr = nr; Pi = ni;
        }
        float t0r = Pr*v6.r0 - Pi*v6.i0, t0i = Pr*v6.i0 + Pi*v6.r0;
        float t1r = Pr*v6.r1 - Pi*v6.i1, t1i = Pr*v6.i1 + Pi*v6.r1;
        ar[0] = t0r*v7.r0 - t0i*v7.i0;  ai[0] = t0r*v7.i0 + t0i*v7.r0;
        ar[1] = t0r*v7.r1 - t0i*v7.i1;  ai[1] = t0r*v7.i1 + t0i*v7.r1;
        ar[2] = t1r*v7.r0 - t1i*v7.i0;  ai[2] = t1r*v7.i0 + t1i*v7.r0;
        ar[3] = t1r*v7.r1 - t1i*v7.i1;  ai[3] = t1r*v7.i1 + t1i*v7.r1;
    }

    run_ops<0>(lane, ar, ai);

    final_wire<0>(cq[0], sq[0], lane, ar, ai);
    final_wire<1>(cq[1], sq[1], lane, ar, ai);
    final_wire<2>(cq[2], sq[2], lane, ar, ai);
    final_wire<3>(cq[3], sq[3], lane, ar, ai);
    final_wire<4>(cq[4], sq[4], lane, ar, ai);
    final_wire<5>(cq[5], sq[5], lane, ar, ai);
    final_wire<6>(cq[6], sq[6], lane, ar, ai);
    final_wire<7>(cq[7], sq[7], lane, ar, ai);

    float p0 = ar[0]*ar[0] + ai[0]*ai[0];
    float p1 = ar[1]*ar[1] + ai[1]*ai[1];
    float p2 = ar[2]*ar[2] + ai[2]*ai[2];
    float p3 = ar[3]*ar[3] + ai[3]*ai[3];
    float pt = p0 + p1 + p2 + p3;
    float a6 = p0 + p1 - p2 - p3;
    float a7 = p0 - p1 + p2 - p3;
    {
        float tv;
        tv = lane_xor<1>(pt, lane);  pt = (lane & 1)  ? (tv - pt) : (tv + pt);
        tv = lane_xor<2>(pt, lane);  pt = (lane & 2)  ? (tv - pt) : (tv + pt);
        tv = lane_xor<4>(pt, lane);  pt = (lane & 4)  ? (tv - pt) : (tv + pt);
        tv = lane_xor<8>(pt, lane);  pt = (lane & 8)  ? (tv - pt) : (tv + pt);
        tv = lane_xor<16>(pt, lane); pt = (lane & 16) ? (tv - pt) : (tv + pt);
        tv = lane_xor<32>(pt, lane); pt = (lane & 32) ? (tv - pt) : (tv + pt);
        a6 += lane_xor<1>(a6, lane);  a6 += lane_xor<2>(a6, lane);
        a6 += lane_xor<4>(a6, lane);  a6 += lane_xor<8>(a6, lane);
        a6 += lane_xor<16>(a6, lane); a6 += lane_xor<32>(a6, lane);
        a7 += lane_xor<1>(a7, lane);  a7 += lane_xor<2>(a7, lane);
        a7 += lane_xor<4>(a7, lane);  a7 += lane_xor<8>(a7, lane);
        a7 += lane_xor<16>(a7, lane); a7 += lane_xor<32>(a7, lane);
    }
    float zl[8];
    zl[0] = __shfl(pt, 32, 64);
    zl[1] = __shfl(pt, 16, 64);
    zl[2] = __shfl(pt, 8, 64);
    zl[3] = __shfl(pt, 4, 64);
    zl[4] = __shfl(pt, 2, 64);
    zl[5] = __shfl(pt, 1, 64);
    zl[6] = a6;
    zl[7] = a7;

    float logit = -1e30f;
    if (lane < T_) {
        logit = b_head[lane];
        #pragma unroll
        for (int w = 0; w < 8; w++)
            logit = fmaf(zl[w], Whead[lane * 8 + w], logit);
    }
    float mx = logit;
    mx = fmaxf(mx, lane_xor<1>(mx, lane));
    mx = fmaxf(mx, lane_xor<2>(mx, lane));
    mx = fmaxf(mx, lane_xor<4>(mx, lane));
    mx = fmaxf(mx, lane_xor<8>(mx, lane));
    float e = (lane < T_) ? __expf(logit - mx) : 0.f;
    float se = e;
    se += lane_xor<1>(se, lane);
    se += lane_xor<2>(se, lane);
    se += lane_xor<4>(se, lane);
    se += lane_xor<8>(se, lane);
    if (lane < T_)
        outrow[lane] = logit - mx - __logf(se);
}

// ===========================================================================
// Single fused pipelined kernel (r12 structure, validated). Wave 0 lanes
// 0..15: all-DPP LSTM scan with RATIONAL gates (3 serial transcendentals/
// step instead of 5) at raised wave priority; waves 1..15: QFC consumers.
// ===========================================================================
__global__ __launch_bounds__(1024) void k_all(
    const float* __restrict__ emb,
    const int* __restrict__ sentence,
    const float* __restrict__ Win,
    const float* __restrict__ b_in,
    const float* __restrict__ phi,
    const float* __restrict__ Wout,
    const float* __restrict__ b_out,
    const float* __restrict__ phiq,
    const float* __restrict__ Whead,
    const float* __restrict__ b_head,
    float* __restrict__ out)
{
    __shared__ float zxs[S_][32];
    __shared__ float sang[S_][8];
    __shared__ int   sprog;

    const int t    = threadIdx.x;
    const int wave = t >> 6;
    const int lane = t & 63;
    const int b    = blockIdx.x;

    if (t == 0) sprog = 0;

    // ---- Phase 1: x-projection, all 16 waves (r12 validated) ----
    {
        const int hw = t >> 5;
        const int l  = t & 31;
        const float4* w4 = (const float4*)(Win + l * FAN_);
        const float cb = b_in[l] + phi[l];
        const int sb = hw * 4;
        const float4* e4_0 = (const float4*)(emb + sentence[(sb + 0) * B_ + b] * E_);
        const float4* e4_1 = (const float4*)(emb + sentence[(sb + 1) * B_ + b] * E_);
        const float4* e4_2 = (const float4*)(emb + sentence[(sb + 2) * B_ + b] * E_);
        const float4* e4_3 = (const float4*)(emb + sentence[(sb + 3) * B_ + b] * E_);
        float a0 = cb, a1 = cb, a2 = cb, a3 = cb;
        #pragma unroll
        for (int f = 0; f < 16; f++) {
            float4 wv = w4[f];
            float4 x0 = e4_0[f];
            float4 x1 = e4_1[f];
            float4 x2 = e4_2[f];
            float4 x3 = e4_3[f];
            a0 = fmaf(x0.x, wv.x, a0); a0 = fmaf(x0.y, wv.y, a0);
            a0 = fmaf(x0.z, wv.z, a0); a0 = fmaf(x0.w, wv.w, a0);
            a1 = fmaf(x1.x, wv.x, a1); a1 = fmaf(x1.y, wv.y, a1);
            a1 = fmaf(x1.z, wv.z, a1); a1 = fmaf(x1.w, wv.w, a1);
            a2 = fmaf(x2.x, wv.x, a2); a2 = fmaf(x2.y, wv.y, a2);
            a2 = fmaf(x2.z, wv.z, a2); a2 = fmaf(x2.w, wv.w, a2);
            a3 = fmaf(x3.x, wv.x, a3); a3 = fmaf(x3.y, wv.y, a3);
            a3 = fmaf(x3.z, wv.z, a3); a3 = fmaf(x3.w, wv.w, a3);
        }
        zxs[sb + 0][l] = a0;
        zxs[sb + 1][l] = a1;
        zxs[sb + 2][l] = a2;
        zxs[sb + 3][l] = a3;
    }
    __syncthreads();

    if (wave == 0) {
        // ---- Producer: all-DPP serial LSTM scan, rational gates ----
        if (lane < 16) {
            __builtin_amdgcn_s_setprio(1);   // don't let polling consumers steal issue slots
            const int j = t & 1;
            const int q = t >> 1;
            const int rowA = j * 8 + q;
            const int rowB = (j + 2) * 8 + q;

            float whA[8], whB[8], woA[8], woB[8];
            #pragma unroll
            for (int k = 0; k < 8; k++) {
                whA[k] = Win[rowA * FAN_ + 64 + k];
                whB[k] = Win[rowB * FAN_ + 64 + k];
                woA[k] = Wout[rowA * 8 + k];
                woB[k] = Wout[rowB * 8 + k];
            }
            const float boA = b_out[rowA];
            const float boB = b_out[rowB];

            float hxv[8];
            #pragma unroll
            for (int k = 0; k < 8; k++) hxv[k] = 0.f;
            float cx = 0.f;

            float zAn = zxs[0][rowA];
            float zBn = zxs[0][rowB];

            for (int s = 0; s < S_; s++) {
                float zA = zAn, zB = zBn;
                const int sn = (s + 1) & (S_ - 1);
                zAn = zxs[sn][rowA];
                zBn = zxs[sn][rowB];

                // z += wh . hxv   (4 chains per slot -> shorter dep chain)
                float za0 = zA, za1 = 0.f, za2 = 0.f, za3 = 0.f;
                float zb0 = zB, zb1 = 0.f, zb2 = 0.f, zb3 = 0.f;
                #pragma unroll
                for (int k = 0; k < 2; k++) {
                    za0 = fmaf(whA[k],     hxv[k],     za0);
                    za1 = fmaf(whA[k + 2], hxv[k + 2], za1);
                    za2 = fmaf(whA[k + 4], hxv[k + 4], za2);
                    za3 = fmaf(whA[k + 6], hxv[k + 6], za3);
                    zb0 = fmaf(whB[k],     hxv[k],     zb0);
                    zb1 = fmaf(whB[k + 2], hxv[k + 2], zb1);
                    zb2 = fmaf(whB[k + 4], hxv[k + 4], zb2);
                    zb3 = fmaf(whB[k + 6], hxv[k + 6], zb3);
                }
                float qcA = __cosf((za0 + za1) + (za2 + za3));
                float qcB = __cosf((zb0 + zb1) + (zb2 + zb3));

                {
                    float uA = dppf<0x112>(qcA), uB = dppf<0x112>(qcB);
                    if (q >= 1) { qcA *= uA; qcB *= uB; }
                    uA = dppf<0x114>(qcA); uB = dppf<0x114>(qcB);
                    if (q >= 2) { qcA *= uA; qcB *= uB; }
                    uA = dppf<0x118>(qcA); uB = dppf<0x118>(qcB);
                    if (q >= 4) { qcA *= uA; qcB *= uB; }
                }

                float cA[8], cB[8];
                bcast8_s2(qcA, t, cA);
                bcast8_s2(qcB, t, cB);

                // pre = bo + wo . c   (4 chains per slot)
                float pa0 = boA, pa1 = 0.f, pa2 = 0.f, pa3 = 0.f;
                float pb0 = boB, pb1 = 0.f, pb2 = 0.f, pb3 = 0.f;
                #pragma unroll
                for (int k = 0; k < 2; k++) {
                    pa0 = fmaf(woA[k],     cA[k],     pa0);
                    pa1 = fmaf(woA[k + 2], cA[k + 2], pa1);
                    pa2 = fmaf(woA[k + 4], cA[k + 4], pa2);
                    pa3 = fmaf(woA[k + 6], cA[k + 6], pa3);
                    pb0 = fmaf(woB[k],     cB[k],     pb0);
                    pb1 = fmaf(woB[k + 2], cB[k + 2], pb1);
                    pb2 = fmaf(woB[k + 4], cB[k + 4], pb2);
                    pb3 = fmaf(woB[k + 6], cB[k + 6], pb3);
                }
                float preA = (pa0 + pa1) + (pa2 + pa3);
                float preB = (pb0 + pb1) + (pb2 + pb3);

                float prA = dppf<0xB1>(preA);
                float prB = dppf<0xB1>(preB);
                float p0 = j ? prA  : preA;
                float p1 = j ? preA : prA;
                float p2 = j ? prB  : preB;
                float p3 = j ? preB : prB;

                float f_ = rat_sigmoid(p0);
                float i_ = rat_sigmoid(p1);
                float g_ = rat_tanh(p2);
                float o_ = rat_sigmoid(p3);
                cx = fmaf(f_, cx, i_ * g_);
                float hnew = o_ * rat_tanh(cx);

                if (j == 0) sang[s][q] = hnew;
                if ((s & 3) == 3) {
                    __threadfence_block();
                    if (t == 0) *(volatile int*)&sprog = s + 1;
                }
                bcast8_s2(hnew, t, hxv);
            }
            __builtin_amdgcn_s_setprio(0);
        }
    } else {
        // ---- Consumers: waves 1..15, rows s = (wave-1) + 15k ----
        float cq[8], sq[8];
        #pragma unroll
        for (int w = 0; w < 8; w++) {
            float ph = phiq[w] * 0.5f;
            cq[w] = __cosf(ph); sq[w] = __sinf(ph);
        }

        for (int s = wave - 1; s < S_; s += 15) {
            while (*(volatile int*)&sprog <= s)
                __builtin_amdgcn_s_sleep(2);
            float th[8];
            #pragma unroll
            for (int w = 0; w < 8; w++) th[w] = sang[s][w] * 0.5f;
            qfc_row(th, cq, sq, lane, Whead, b_head, out + (b * S_ + s) * T_);
        }
    }
}

// ---------------------------------------------------------------------------
extern "C" void kernel_launch(void* const* d_in, const int* in_sizes, int n_in,
                              void* d_out, int out_size, void* d_ws, size_t ws_size,
                              hipStream_t stream)
{
    (void)in_sizes; (void)n_in; (void)out_size; (void)d_ws; (void)ws_size;
    const float* emb    = (const float*)d_in[0];
    const float* Win    = (const float*)d_in[1];
    const float* b_in   = (const float*)d_in[2];
    const float* phi    = (const float*)d_in[3];
    const float* Wout   = (const float*)d_in[4];
    const float* b_out  = (const float*)d_in[5];
    const float* phiq   = (const float*)d_in[6];
    const float* Whead  = (const float*)d_in[7];
    const float* b_head = (const float*)d_in[8];
    const int* sentence = (const int*)d_in[9];
    float* out          = (float*)d_out;

    hipLaunchKernelGGL(k_all, dim3(B_), dim3(1024), 0, stream,
                       emb, sentence, Win, b_in, phi, Wout, b_out,
                       phiq, Whead, b_head, out);
}

// Round 14
// 155.580 us; speedup vs baseline: 1.0533x; 1.0533x over previous
//
#include <hip/hip_runtime.h>
#include <math.h>
#include <stdint.h>

#define S_    128
#define B_    128
#define E_    64
#define H_    8
#define T_    12
#define FAN_  72
#define NOPS_ 30
#define MAXG_ 30
#define NROWS_ (S_ * B_)

// ===========================================================================
// COMPILE-TIME circuit (validated r8-r13): MT19937(1234) + optimizer.
// ===========================================================================
constexpr double CT_PI = 3.14159265358979323846;

constexpr double ct_cos(double x) {
    double t = 1.0, s = 1.0, x2 = x * x;
    for (int k = 1; k <= 20; k++) { t *= -x2 / ((2.0*k - 1.0) * (2.0*k)); s += t; }
    return s;
}
constexpr double ct_sin(double x) {
    double t = x, s = x, x2 = x * x;
    for (int k = 1; k <= 20; k++) { t *= -x2 / ((2.0*k) * (2.0*k + 1.0)); s += t; }
    return s;
}

constexpr void ct_mmul(const double* A, const double* B, double* C) {
    for (int i = 0; i < 2; i++)
        for (int j = 0; j < 2; j++) {
            double rr = 0.0, ii = 0.0;
            for (int k = 0; k < 2; k++) {
                double ar = A[(i*2+k)*2], ai = A[(i*2+k)*2+1];
                double br = B[(k*2+j)*2], bi = B[(k*2+j)*2+1];
                rr += ar*br - ai*bi;
                ii += ar*bi + ai*br;
            }
            C[(i*2+j)*2] = rr; C[(i*2+j)*2+1] = ii;
        }
}

struct CTC {
    int n;
    int type[MAXG_];
    int w1[MAXG_];
    int w2[MAXG_];
    double U[MAXG_][8];
    double initM[8][8];
    double endM[8][8];
};

constexpr CTC build_ct() {
    uint32_t mt[624] = {};
    int idx = 624;
    {
        uint32_t s = 1234u;
        for (int i = 0; i < 624; i++) {
            mt[i] = s;
            s = 1812433253u * (s ^ (s >> 30)) + (uint32_t)i + 1u;
        }
    }
    auto nextf = [&]() -> uint32_t {
        if (idx >= 624) {
            for (int i = 0; i < 624; i++) {
                uint32_t y = (mt[i] & 0x80000000u) | (mt[(i+1)%624] & 0x7fffffffu);
                uint32_t v = mt[(i+397)%624] ^ (y >> 1);
                mt[i] = (y & 1u) ? (v ^ 0x9908b0dfu) : v;
            }
            idx = 0;
        }
        uint32_t y = mt[idx++];
        y ^= y >> 11;
        y ^= (y << 7)  & 0x9d2c5680u;
        y ^= (y << 15) & 0xefc60000u;
        y ^= y >> 18;
        return y;
    };
    auto randint = [&](uint32_t n) -> uint32_t {
        uint32_t rng = n - 1u, mask = rng;
        mask |= mask >> 1; mask |= mask >> 2; mask |= mask >> 4;
        mask |= mask >> 8; mask |= mask >> 16;
        uint32_t v = 0;
        do { v = nextf() & mask; } while (v > rng);
        return v;
    };
    auto uniform2pi = [&]() -> double {
        uint32_t a = nextf() >> 5;
        uint32_t b = nextf() >> 6;
        double d = ((double)a * 67108864.0 + (double)b) / 9007199254740992.0;
        return 2.0 * CT_PI * d;
    };

    int kindA[NOPS_] = {}, aA[NOPS_] = {}, bA[NOPS_] = {};
    double UA[NOPS_][8] = {};
    for (int i = 0; i < NOPS_; i++) {
        uint32_t kind = randint(4);
        if (kind == 3u) {
            int c = (int)randint(8);
            int t = (int)randint(7);
            if (t >= c) t += 1;
            kindA[i] = 1; aA[i] = c; bA[i] = t;
            UA[i][0] = 1.0; UA[i][6] = 1.0;
        } else {
            int g = (int)(kind % 3u);
            int w = (int)randint(8);
            double th = uniform2pi();
            double c = ct_cos(0.5 * th), s = ct_sin(0.5 * th);
            kindA[i] = 0; aA[i] = w; bA[i] = -1;
            if (g == 0)      { UA[i][0]=c;  UA[i][3]=-s; UA[i][5]=-s; UA[i][6]=c; }
            else if (g == 1) { UA[i][0]=c;  UA[i][2]=-s; UA[i][4]= s; UA[i][6]=c; }
            else             { UA[i][0]=c;  UA[i][1]=-s; UA[i][6]= c; UA[i][7]=s; }
        }
    }

    int ikind[MAXG_] = {}, ia[MAXG_] = {}, ib[MAXG_] = {};
    double iU[MAXG_][8] = {};
    int cnt = 0;
    double initM[8][8] = {}, endM[8][8] = {};
    for (int w = 0; w < 8; w++) { initM[w][0] = 1.0; initM[w][6] = 1.0;
                                  endM[w][0]  = 1.0; endM[w][6]  = 1.0; }

    for (int oi = 0; oi < NOPS_; oi++) {
        if (kindA[oi] == 0) {
            int w = aA[oi], k = cnt - 1;
            bool merged = false;
            while (k >= 0) {
                if (ikind[k] == 0) {
                    if (ia[k] == w) {
                        double tmp[8] = {};
                        ct_mmul(UA[oi], iU[k], tmp);
                        for (int j = 0; j < 8; j++) iU[k][j] = tmp[j];
                        merged = true; break;
                    }
                    k--;
                } else {
                    if (w == ia[k] || w == ib[k]) break;
                    k--;
                }
            }
            if (merged) continue;
            if (k < 0) {
                double tmp[8] = {};
                ct_mmul(UA[oi], initM[w], tmp);
                for (int j = 0; j < 8; j++) initM[w][j] = tmp[j];
                continue;
            }
            ikind[cnt] = 0; ia[cnt] = w; ib[cnt] = -1;
            for (int j = 0; j < 8; j++) iU[cnt][j] = UA[oi][j];
            cnt++;
        } else {
            int c = aA[oi], t2 = bA[oi], k = cnt - 1;
            bool cancelled = false;
            while (k >= 0) {
                if (ikind[k] == 0) {
                    int w = ia[k];
                    if (w == c || w == t2) break;
                    k--;
                } else {
                    int c2 = ia[k], tt = ib[k];
                    if (c2 == c && tt == t2) {
                        for (int m = k; m < cnt - 1; m++) {
                            ikind[m] = ikind[m+1]; ia[m] = ia[m+1]; ib[m] = ib[m+1];
                            for (int j = 0; j < 8; j++) iU[m][j] = iU[m+1][j];
                        }
                        cnt--; cancelled = true; break;
                    }
                    if (c2 != t2 && tt != c) k--;
                    else break;
                }
            }
            if (!cancelled) {
                ikind[cnt] = 1; ia[cnt] = c; ib[cnt] = t2;
                for (int j = 0; j < 8; j++) iU[cnt][j] = 0.0;
                iU[cnt][0] = 1.0; iU[cnt][6] = 1.0;
                cnt++;
            }
        }
    }
    bool blocked[8] = {};
    for (int k = cnt - 1; k >= 0; k--) {
        if (ikind[k] == 0) {
            int w = ia[k];
            if (!blocked[w]) {
                double tmp[8] = {};
                ct_mmul(endM[w], iU[k], tmp);
                for (int j = 0; j < 8; j++) endM[w][j] = tmp[j];
                for (int m = k; m < cnt - 1; m++) {
                    ikind[m] = ikind[m+1]; ia[m] = ia[m+1]; ib[m] = ib[m+1];
                    for (int j = 0; j < 8; j++) iU[m][j] = iU[m+1][j];
                }
                cnt--;
            }
        } else {
            blocked[ia[k]] = true; blocked[ib[k]] = true;
        }
    }

    CTC q = {};
    q.n = cnt;
    for (int i = 0; i < cnt; i++) {
        q.type[i] = ikind[i]; q.w1[i] = ia[i]; q.w2[i] = ib[i];
        for (int j = 0; j < 8; j++) q.U[i][j] = iU[i][j];
    }
    for (int w = 0; w < 8; w++)
        for (int j = 0; j < 8; j++) { q.initM[w][j] = initM[w][j]; q.endM[w][j] = endM[w][j]; }
    return q;
}

constexpr CTC CIRC = build_ct();

// ===========================================================================
// Device helpers (validated r5-r12)
// ===========================================================================
#define LOG2E_  1.4426950408889634f
#define LOG2E2_ 2.8853900817779268f

__device__ __forceinline__ float fast_sigmoid(float x) {
    return __builtin_amdgcn_rcpf(1.f + __builtin_amdgcn_exp2f(-LOG2E_ * x));
}
__device__ __forceinline__ float fast_tanh(float x) {
    return 1.f - 2.f * __builtin_amdgcn_rcpf(1.f + __builtin_amdgcn_exp2f(LOG2E2_ * x));
}

template<int CTRL>
__device__ __forceinline__ float dppf(float x) {
    union { float f; int i; } u, r;
    u.f = x;
    r.i = __builtin_amdgcn_update_dpp(u.i, u.i, CTRL, 0xF, 0xF, true);
    return r.f;
}

template<int M>
__device__ __forceinline__ float lane_xor(float x, int lane) {
    if constexpr (M == 1)  return dppf<0xB1>(x);
    else if constexpr (M == 2) return dppf<0x4E>(x);
    else if constexpr (M == 4) {
        float a = dppf<0x104>(x);
        float b = dppf<0x114>(x);
        return (lane & 4) ? b : a;
    }
    else if constexpr (M == 8) return dppf<0x128>(x);
    else return __shfl_xor(x, M, 64);
}

template<int W>
__device__ __forceinline__ float exch(float x, int lane) {
    if constexpr (W == 0) return __shfl_xor(x, 32, 64);
    else if constexpr (W == 1) return __shfl_xor(x, 16, 64);
    else if constexpr (W == 2) return lane_xor<8>(x, lane);
    else if constexpr (W == 3) return lane_xor<4>(x, lane);
    else if constexpr (W == 4) return lane_xor<2>(x, lane);
    else return lane_xor<1>(x, lane);
}

template<int W>
__device__ __forceinline__ int qbit_ct(int lane, int j) {
    if constexpr (W < 6) return (lane >> (5 - W)) & 1;
    else if constexpr (W == 6) return (j >> 1) & 1;
    else return j & 1;
}

__device__ __forceinline__ void pair_rt(float u0, float u1, float u2, float u3,
                                        float u4, float u5, float u6, float u7,
                                        float& a0r, float& a0i, float& a1r, float& a1i) {
    float n0r = u0*a0r - u1*a0i + u2*a1r - u3*a1i;
    float n0i = u0*a0i + u1*a0r + u2*a1i + u3*a1r;
    float n1r = u4*a0r - u5*a0i + u6*a1r - u7*a1i;
    float n1i = u4*a0i + u5*a0r + u6*a1i + u7*a1r;
    a0r = n0r; a0i = n0i; a1r = n1r; a1i = n1i;
}

template<int W>
__device__ __forceinline__ void gate_rt(float u0, float u1, float u2, float u3,
                                        float u4, float u5, float u6, float u7,
                                        int lane, float ar[4], float ai[4]) {
    if constexpr (W < 6) {
        const int b = (lane >> (5 - W)) & 1;
        const float dr  = b ? u6 : u0;
        const float di  = b ? u7 : u1;
        const float onr = b ? u4 : u2;
        const float oni = b ? u5 : u3;
        #pragma unroll
        for (int j = 0; j < 4; j++) {
            float br = exch<W>(ar[j], lane);
            float bi = exch<W>(ai[j], lane);
            float nr = dr * ar[j] - di * ai[j] + onr * br - oni * bi;
            float ni = dr * ai[j] + di * ar[j] + onr * bi + oni * br;
            ar[j] = nr; ai[j] = ni;
        }
    } else if constexpr (W == 6) {
        pair_rt(u0,u1,u2,u3,u4,u5,u6,u7, ar[0], ai[0], ar[2], ai[2]);
        pair_rt(u0,u1,u2,u3,u4,u5,u6,u7, ar[1], ai[1], ar[3], ai[3]);
    } else {
        pair_rt(u0,u1,u2,u3,u4,u5,u6,u7, ar[0], ai[0], ar[1], ai[1]);
        pair_rt(u0,u1,u2,u3,u4,u5,u6,u7, ar[2], ai[2], ar[3], ai[3]);
    }
}

template<int CW, int TW>
__device__ __forceinline__ void cnot_ct(int lane, float ar[4], float ai[4]) {
    if constexpr (TW < 6) {
        #pragma unroll
        for (int j = 0; j < 4; j++) {
            float br = exch<TW>(ar[j], lane);
            float bi = exch<TW>(ai[j], lane);
            int ctrl = qbit_ct<CW>(lane, j);
            ar[j] = ctrl ? br : ar[j];
            ai[j] = ctrl ? bi : ai[j];
        }
    } else if constexpr (TW == 6) {
        int cA = qbit_ct<CW>(lane, 0), cB = qbit_ct<CW>(lane, 1);
        float n0r = cA ? ar[2] : ar[0], n0i = cA ? ai[2] : ai[0];
        float n2r = cA ? ar[0] : ar[2], n2i = cA ? ai[0] : ai[2];
        float n1r = cB ? ar[3] : ar[1], n1i = cB ? ai[3] : ai[1];
        float n3r = cB ? ar[1] : ar[3], n3i = cB ? ai[1] : ai[3];
        ar[0]=n0r; ai[0]=n0i; ar[1]=n1r; ai[1]=n1i;
        ar[2]=n2r; ai[2]=n2i; ar[3]=n3r; ai[3]=n3i;
    } else {
        int cA = qbit_ct<CW>(lane, 0), cB = qbit_ct<CW>(lane, 2);
        float n0r = cA ? ar[1] : ar[0], n0i = cA ? ai[1] : ai[0];
        float n1r = cA ? ar[0] : ar[1], n1i = cA ? ai[0] : ai[1];
        float n2r = cB ? ar[3] : ar[2], n2i = cB ? ai[3] : ai[2];
        float n3r = cB ? ar[2] : ar[3], n3i = cB ? ai[2] : ai[3];
        ar[0]=n0r; ai[0]=n0i; ar[1]=n1r; ai[1]=n1i;
        ar[2]=n2r; ai[2]=n2i; ar[3]=n3r; ai[3]=n3i;
    }
}

template<int I>
__device__ __forceinline__ void gate_op(int lane, float ar[4], float ai[4]) {
    constexpr int w = CIRC.w1[I];
    constexpr float u0 = (float)CIRC.U[I][0], u1 = (float)CIRC.U[I][1];
    constexpr float u2 = (float)CIRC.U[I][2], u3 = (float)CIRC.U[I][3];
    constexpr float u4 = (float)CIRC.U[I][4], u5 = (float)CIRC.U[I][5];
    constexpr float u6 = (float)CIRC.U[I][6], u7 = (float)CIRC.U[I][7];
    gate_rt<w>(u0,u1,u2,u3,u4,u5,u6,u7, lane, ar, ai);
}

template<int I>
__device__ __forceinline__ void run_ops(int lane, float ar[4], float ai[4]) {
    if constexpr (I < CIRC.n) {
        if constexpr (CIRC.type[I] == 0) gate_op<I>(lane, ar, ai);
        else cnot_ct<CIRC.w1[I], CIRC.w2[I]>(lane, ar, ai);
        run_ops<I + 1>(lane, ar, ai);
    }
}

struct V2 { float r0, i0, r1, i1; };
template<int W>
__device__ __forceinline__ V2 init_wire(float th) {
    constexpr float m0 = (float)CIRC.initM[W][0], m1 = (float)CIRC.initM[W][1];
    constexpr float m2 = (float)CIRC.initM[W][2], m3 = (float)CIRC.initM[W][3];
    constexpr float m4 = (float)CIRC.initM[W][4], m5 = (float)CIRC.initM[W][5];
    constexpr float m6 = (float)CIRC.initM[W][6], m7 = (float)CIRC.initM[W][7];
    float c = __cosf(th), s = __sinf(th);
    V2 v;
    v.r0 = m0*c + m2*s; v.i0 = m1*c + m3*s;
    v.r1 = m4*c + m6*s; v.i1 = m5*c + m7*s;
    return v;
}

template<int W>
__device__ __forceinline__ void final_wire(float c, float s, int lane,
                                           float ar[4], float ai[4]) {
    constexpr float E0 = (float)CIRC.endM[W][0], E1 = (float)CIRC.endM[W][1];
    constexpr float E2 = (float)CIRC.endM[W][2], E3 = (float)CIRC.endM[W][3];
    constexpr float E4 = (float)CIRC.endM[W][4], E5 = (float)CIRC.endM[W][5];
    constexpr float E6 = (float)CIRC.endM[W][6], E7 = (float)CIRC.endM[W][7];
    float F0 =  c*E0 + s*E5;
    float F1 =  c*E1 - s*E4;
    float F2 =  c*E2 + s*E7;
    float F3 =  c*E3 - s*E6;
    float F4 =  s*E1 + c*E4;
    float F5 = -s*E0 + c*E5;
    float F6 =  s*E3 + c*E6;
    float F7 = -s*E2 + c*E7;
    gate_rt<W>(F0,F1,F2,F3,F4,F5,F6,F7, lane, ar, ai);
}

// stride-2 all-gather of 8 values (validated r10-r12)
__device__ __forceinline__ void bcast8_s2(float v, int lane, float h[8]) {
    float p  = lane_xor<2>(v, lane);
    float a0 = (lane & 2) ? p : v;
    float a1 = (lane & 2) ? v : p;
    float q0 = lane_xor<4>(a0, lane);
    float q1 = lane_xor<4>(a1, lane);
    float b0 = (lane & 4) ? q0 : a0;
    float b1 = (lane & 4) ? q1 : a1;
    float b2 = (lane & 4) ? a0 : q0;
    float b3 = (lane & 4) ? a1 : q1;
    float r0 = lane_xor<8>(b0, lane);
    float r1 = lane_xor<8>(b1, lane);
    float r2 = lane_xor<8>(b2, lane);
    float r3 = lane_xor<8>(b3, lane);
    h[0] = (lane & 8) ? r0 : b0;  h[1] = (lane & 8) ? r1 : b1;
    h[2] = (lane & 8) ? r2 : b2;  h[3] = (lane & 8) ? r3 : b3;
    h[4] = (lane & 8) ? b0 : r0;  h[5] = (lane & 8) ? b1 : r1;
    h[6] = (lane & 8) ? b2 : r2;  h[7] = (lane & 8) ? b3 : r3;
}

// QFC body for one row (validated r8-r12)
__device__ __forceinline__ void qfc_row(const float th[8],
    float cq[8], float sq[8], int lane,
    const float* __restrict__ Whead, const float* __restrict__ b_head,
    float* __restrict__ outrow)
{
    float ar[4], ai[4];
    {
        V2 v0 = init_wire<0>(th[0]);
        V2 v1 = init_wire<1>(th[1]);
        V2 v2 = init_wire<2>(th[2]);
        V2 v3 = init_wire<3>(th[3]);
        V2 v4 = init_wire<4>(th[4]);
        V2 v5 = init_wire<5>(th[5]);
        V2 v6 = init_wire<6>(th[6]);
        V2 v7 = init_wire<7>(th[7]);
        float Pr = 1.f, Pi = 0.f;
        {
            int bit = (lane >> 5) & 1;
            float er = bit ? v0.r1 : v0.r0, ei = bit ? v0.i1 : v0.i0;
            float nr = Pr*er - Pi*ei, ni = Pr*ei + Pi*er; Pr = nr; Pi = ni;
        }
        {
            int bit = (lane >> 4) & 1;
            float er = bit ? v1.r1 : v1.r0, ei = bit ? v1.i1 : v1.i0;
            float nr = Pr*er - Pi*ei, ni = Pr*ei + Pi*er; Pr = nr; Pi = ni;
        }
        {
            int bit = (lane >> 3) & 1;
            float er = bit ? v2.r1 : v2.r0, ei = bit ? v2.i1 : v2.i0;
            float nr = Pr*er - Pi*ei, ni = Pr*ei + Pi*er; Pr = nr; Pi = ni;
        }
        {
            int bit = (lane >> 2) & 1;
            float er = bit ? v3.r1 : v3.r0, ei = bit ? v3.i1 : v3.i0;
            float nr = Pr*er - Pi*ei, ni = Pr*ei + Pi*er; Pr = nr; Pi = ni;
        }
        {
            int bit = (lane >> 1) & 1;
            float er = bit ? v4.r1 : v4.r0, ei = bit ? v4.i1 : v4.i0;
            float nr = Pr*er - Pi*ei, ni = Pr*ei + Pi*er; Pr = nr; Pi = ni;
        }
        {
            int bit = lane & 1;
            float er = bit ? v5.r1 : v5.r0, ei = bit ? v5.i1 : v5.i0;
            float nr = Pr*er - Pi*ei, ni = Pr*ei + Pi*er; Pr = nr; Pi = ni;
        }
        float t0r = Pr*v6.r0 - Pi*v6.i0, t0i = Pr*v6.i0 + Pi*v6.r0;
        float t1r = Pr*v6.r1 - Pi*v6.i1, t1i = Pr*v6.i1 + Pi*v6.r1;
        ar[0] = t0r*v7.r0 - t0i*v7.i0;  ai[0] = t0r*v7.i0 + t0i*v7.r0;
        ar[1] = t0r*v7.r1 - t0i*v7.i1;  ai[1] = t0r*v7.i1 + t0i*v7.r1;
        ar[2] = t1r*v7.r0 - t1i*v7.i0;  ai[2] = t1r*v7.i0 + t1i*v7.r0;
        ar[3] = t1r*v7.r1 - t1i*v7.i1;  ai[3] = t1r*v7.i1 + t1i*v7.r1;
    }

    run_ops<0>(lane, ar, ai);

    final_wire<0>(cq[0], sq[0], lane, ar, ai);
    final_wire<1>(cq[1], sq[1], lane, ar, ai);
    final_wire<2>(cq[2], sq[2], lane, ar, ai);
    final_wire<3>(cq[3], sq[3], lane, ar, ai);
    final_wire<4>(cq[4], sq[4], lane, ar, ai);
    final_wire<5>(cq[5], sq[5], lane, ar, ai);
    final_wire<6>(cq[6], sq[6], lane, ar, ai);
    final_wire<7>(cq[7], sq[7], lane, ar, ai);

    float p0 = ar[0]*ar[0] + ai[0]*ai[0];
    float p1 = ar[1]*ar[1] + ai[1]*ai[1];
    float p2 = ar[2]*ar[2] + ai[2]*ai[2];
    float p3 = ar[3]*ar[3] + ai[3]*ai[3];
    float pt = p0 + p1 + p2 + p3;
    float a6 = p0 + p1 - p2 - p3;
    float a7 = p0 - p1 + p2 - p3;
    {
        float tv;
        tv = lane_xor<1>(pt, lane);  pt = (lane & 1)  ? (tv - pt) : (tv + pt);
        tv = lane_xor<2>(pt, lane);  pt = (lane & 2)  ? (tv - pt) : (tv + pt);
        tv = lane_xor<4>(pt, lane);  pt = (lane & 4)  ? (tv - pt) : (tv + pt);
        tv = lane_xor<8>(pt, lane);  pt = (lane & 8)  ? (tv - pt) : (tv + pt);
        tv = lane_xor<16>(pt, lane); pt = (lane & 16) ? (tv - pt) : (tv + pt);
        tv = lane_xor<32>(pt, lane); pt = (lane & 32) ? (tv - pt) : (tv + pt);
        a6 += lane_xor<1>(a6, lane);  a6 += lane_xor<2>(a6, lane);
        a6 += lane_xor<4>(a6, lane);  a6 += lane_xor<8>(a6, lane);
        a6 += lane_xor<16>(a6, lane); a6 += lane_xor<32>(a6, lane);
        a7 += lane_xor<1>(a7, lane);  a7 += lane_xor<2>(a7, lane);
        a7 += lane_xor<4>(a7, lane);  a7 += lane_xor<8>(a7, lane);
        a7 += lane_xor<16>(a7, lane); a7 += lane_xor<32>(a7, lane);
    }
    float zl[8];
    zl[0] = __shfl(pt, 32, 64);
    zl[1] = __shfl(pt, 16, 64);
    zl[2] = __shfl(pt, 8, 64);
    zl[3] = __shfl(pt, 4, 64);
    zl[4] = __shfl(pt, 2, 64);
    zl[5] = __shfl(pt, 1, 64);
    zl[6] = a6;
    zl[7] = a7;

    float logit = -1e30f;
    if (lane < T_) {
        logit = b_head[lane];
        #pragma unroll
        for (int w = 0; w < 8; w++)
            logit = fmaf(zl[w], Whead[lane * 8 + w], logit);
    }
    float mx = logit;
    mx = fmaxf(mx, lane_xor<1>(mx, lane));
    mx = fmaxf(mx, lane_xor<2>(mx, lane));
    mx = fmaxf(mx, lane_xor<4>(mx, lane));
    mx = fmaxf(mx, lane_xor<8>(mx, lane));
    float e = (lane < T_) ? __expf(logit - mx) : 0.f;
    float se = e;
    se += lane_xor<1>(se, lane);
    se += lane_xor<2>(se, lane);
    se += lane_xor<4>(se, lane);
    se += lane_xor<8>(se, lane);
    if (lane < T_)
        outrow[lane] = logit - mx - __logf(se);
}

// ===========================================================================
// Single fused pipelined kernel (r12, validated @90.4us kernel / 155.8 bench).
// Wave 0 lanes 0..15: all-DPP LSTM scan with exp2/rcp fast gates, publishing
// progress every 4 steps. Waves 1..15: QFC consumers on block-local LDS.
// ===========================================================================
__global__ __launch_bounds__(1024) void k_all(
    const float* __restrict__ emb,
    const int* __restrict__ sentence,
    const float* __restrict__ Win,
    const float* __restrict__ b_in,
    const float* __restrict__ phi,
    const float* __restrict__ Wout,
    const float* __restrict__ b_out,
    const float* __restrict__ phiq,
    const float* __restrict__ Whead,
    const float* __restrict__ b_head,
    float* __restrict__ out)
{
    __shared__ float zxs[S_][32];
    __shared__ float sang[S_][8];
    __shared__ int   sprog;

    const int t    = threadIdx.x;
    const int wave = t >> 6;
    const int lane = t & 63;
    const int b    = blockIdx.x;

    if (t == 0) sprog = 0;

    // ---- Phase 1: x-projection, all 16 waves ----
    {
        const int hw = t >> 5;
        const int l  = t & 31;
        const float4* w4 = (const float4*)(Win + l * FAN_);
        const float cb = b_in[l] + phi[l];
        const int sb = hw * 4;
        const float4* e4_0 = (const float4*)(emb + sentence[(sb + 0) * B_ + b] * E_);
        const float4* e4_1 = (const float4*)(emb + sentence[(sb + 1) * B_ + b] * E_);
        const float4* e4_2 = (const float4*)(emb + sentence[(sb + 2) * B_ + b] * E_);
        const float4* e4_3 = (const float4*)(emb + sentence[(sb + 3) * B_ + b] * E_);
        float a0 = cb, a1 = cb, a2 = cb, a3 = cb;
        #pragma unroll
        for (int f = 0; f < 16; f++) {
            float4 wv = w4[f];
            float4 x0 = e4_0[f];
            float4 x1 = e4_1[f];
            float4 x2 = e4_2[f];
            float4 x3 = e4_3[f];
            a0 = fmaf(x0.x, wv.x, a0); a0 = fmaf(x0.y, wv.y, a0);
            a0 = fmaf(x0.z, wv.z, a0); a0 = fmaf(x0.w, wv.w, a0);
            a1 = fmaf(x1.x, wv.x, a1); a1 = fmaf(x1.y, wv.y, a1);
            a1 = fmaf(x1.z, wv.z, a1); a1 = fmaf(x1.w, wv.w, a1);
            a2 = fmaf(x2.x, wv.x, a2); a2 = fmaf(x2.y, wv.y, a2);
            a2 = fmaf(x2.z, wv.z, a2); a2 = fmaf(x2.w, wv.w, a2);
            a3 = fmaf(x3.x, wv.x, a3); a3 = fmaf(x3.y, wv.y, a3);
            a3 = fmaf(x3.z, wv.z, a3); a3 = fmaf(x3.w, wv.w, a3);
        }
        zxs[sb + 0][l] = a0;
        zxs[sb + 1][l] = a1;
        zxs[sb + 2][l] = a2;
        zxs[sb + 3][l] = a3;
    }
    __syncthreads();

    if (wave == 0) {
        // ---- Producer: all-DPP serial LSTM scan (lanes 0..15), fast gates ----
        if (lane < 16) {
            const int j = t & 1;
            const int q = t >> 1;
            const int rowA = j * 8 + q;
            const int rowB = (j + 2) * 8 + q;

            float whA[8], whB[8], woA[8], woB[8];
            #pragma unroll
            for (int k = 0; k < 8; k++) {
                whA[k] = Win[rowA * FAN_ + 64 + k];
                whB[k] = Win[rowB * FAN_ + 64 + k];
                woA[k] = Wout[rowA * 8 + k];
                woB[k] = Wout[rowB * 8 + k];
            }
            const float boA = b_out[rowA];
            const float boB = b_out[rowB];

            float hxv[8];
            #pragma unroll
            for (int k = 0; k < 8; k++) hxv[k] = 0.f;
            float cx = 0.f;

            float zAn = zxs[0][rowA];
            float zBn = zxs[0][rowB];

            for (int s = 0; s < S_; s++) {
                float zA = zAn, zB = zBn;
                const int sn = (s + 1) & (S_ - 1);
                zAn = zxs[sn][rowA];
                zBn = zxs[sn][rowB];

                float za0 = zA, za1 = 0.f, zb0 = zB, zb1 = 0.f;
                #pragma unroll
                for (int k = 0; k < 4; k++) {
                    za0 = fmaf(whA[k], hxv[k], za0);
                    za1 = fmaf(whA[k + 4], hxv[k + 4], za1);
                    zb0 = fmaf(whB[k], hxv[k], zb0);
                    zb1 = fmaf(whB[k + 4], hxv[k + 4], zb1);
                }
                float qcA = __cosf(za0 + za1);
                float qcB = __cosf(zb0 + zb1);

                {
                    float uA = dppf<0x112>(qcA), uB = dppf<0x112>(qcB);
                    if (q >= 1) { qcA *= uA; qcB *= uB; }
                    uA = dppf<0x114>(qcA); uB = dppf<0x114>(qcB);
                    if (q >= 2) { qcA *= uA; qcB *= uB; }
                    uA = dppf<0x118>(qcA); uB = dppf<0x118>(qcB);
                    if (q >= 4) { qcA *= uA; qcB *= uB; }
                }

                float cA[8], cB[8];
                bcast8_s2(qcA, t, cA);
                bcast8_s2(qcB, t, cB);

                float pa0 = boA, pa1 = 0.f, pb0 = boB, pb1 = 0.f;
                #pragma unroll
                for (int k = 0; k < 4; k++) {
                    pa0 = fmaf(woA[k], cA[k], pa0);
                    pa1 = fmaf(woA[k + 4], cA[k + 4], pa1);
                    pb0 = fmaf(woB[k], cB[k], pb0);
                    pb1 = fmaf(woB[k + 4], cB[k + 4], pb1);
                }
                float preA = pa0 + pa1;
                float preB = pb0 + pb1;

                float prA = dppf<0xB1>(preA);
                float prB = dppf<0xB1>(preB);
                float p0 = j ? prA  : preA;
                float p1 = j ? preA : prA;
                float p2 = j ? prB  : preB;
                float p3 = j ? preB : prB;

                float f_ = fast_sigmoid(p0);
                float i_ = fast_sigmoid(p1);
                float g_ = fast_tanh(p2);
                float o_ = fast_sigmoid(p3);
                cx = fmaf(f_, cx, i_ * g_);
                float hnew = o_ * fast_tanh(cx);

                if (j == 0) sang[s][q] = hnew;
                if ((s & 3) == 3) {
                    __threadfence_block();
                    if (t == 0) *(volatile int*)&sprog = s + 1;
                }
                bcast8_s2(hnew, t, hxv);
            }
        }
    } else {
        // ---- Consumers: waves 1..15, rows s = (wave-1) + 15k ----
        float cq[8], sq[8];
        #pragma unroll
        for (int w = 0; w < 8; w++) {
            float ph = phiq[w] * 0.5f;
            cq[w] = __cosf(ph); sq[w] = __sinf(ph);
        }

        for (int s = wave - 1; s < S_; s += 15) {
            while (*(volatile int*)&sprog <= s)
                __builtin_amdgcn_s_sleep(2);
            float th[8];
            #pragma unroll
            for (int w = 0; w < 8; w++) th[w] = sang[s][w] * 0.5f;
            qfc_row(th, cq, sq, lane, Whead, b_head, out + (b * S_ + s) * T_);
        }
    }
}

// ---------------------------------------------------------------------------
extern "C" void kernel_launch(void* const* d_in, const int* in_sizes, int n_in,
                              void* d_out, int out_size, void* d_ws, size_t ws_size,
                              hipStream_t stream)
{
    (void)in_sizes; (void)n_in; (void)out_size; (void)d_ws; (void)ws_size;
    const float* emb    = (const float*)d_in[0];
    const float* Win    = (const float*)d_in[1];
    const float* b_in   = (const float*)d_in[2];
    const float* phi    = (const float*)d_in[3];
    const float* Wout   = (const float*)d_in[4];
    const float* b_out  = (const float*)d_in[5];
    const float* phiq   = (const float*)d_in[6];
    const float* Whead  = (const float*)d_in[7];
    const float* b_head = (const float*)d_in[8];
    const int* sentence = (const int*)d_in[9];
    float* out          = (float*)d_out;

    hipLaunchKernelGGL(k_all, dim3(B_), dim3(1024), 0, stream,
                       emb, sentence, Win, b_in, phi, Wout, b_out,
                       phiq, Whead, b_head, out);
}